// Round 17
// baseline (367.277 us; speedup 1.0000x reference)
//
#include <hip/hip_runtime.h>
#include <math.h>

// PhaseNN on MI355X.  ROUND 28: 2 blocks/CU (T2L halved to ct<32 -> LDS 71 KB).
// R27 re-verified R25 at ~318-346 us: VALU 55 / MFMA 18.5 / HBM 0.65 /
// OCCUPANCY 47% -- per-eval critical path ~11,900 cyc holds only ~3,200 cyc of
// pipe work; the 3.5x slack is barrier-drain + dependency latency.  Occupancy
// is capped ONLY by LDS (138 KB > 80 KB); VGPR=60 fits the 8-wave/EU budget,
// threads 2x1024 = 2048 cap exactly.
// R28: T2 ct 32..63 -> global i4 (R24 showed this stream is ~free: removing it
// was neutral); LDS 138 -> 71 KB -> 2 blocks/CU; block A's barriers overlap
// block B's compute.  Aggregate L2 ~12 TB/s << 34.5 cap.
// Values bit-identical -> absmax must stay EXACTLY 0.015625.
// Verification signal: Occupancy ~47 -> ~85-95 (stays 47 => cap didn't lift,
// revert).  Tripwire: WRITE > 4 MB = spill.
// Structure: 256 blocks x 1 row, 16 waves, i8-MFMA K=64, 3 barriers/eval,
// T1 global i2 64K; T2 i4 split: ct<32 LDS (64K) / ct>=32 global (64K).

typedef __attribute__((ext_vector_type(4))) float f32x4;
typedef __attribute__((ext_vector_type(4))) int   i32x4;
typedef __attribute__((ext_vector_type(2))) int   i32x2;
typedef __attribute__((ext_vector_type(8))) short bf16x8;

struct TCons { float s[64]; float c[64]; };

__device__ __forceinline__ unsigned short f2bf(float f) {
  unsigned u = __builtin_bit_cast(unsigned, f);
  return (unsigned short)((u + 0x7FFFu + ((u >> 16) & 1u)) >> 16);
}

#define A1_OFF    0        // feats: GEMM1 i8 [cos 1024 | sin 1024]; epilogue bf16 [cos 2048 | sin 2048]
#define MBUF_OFF  4096     // m partials i32: 2 kh x 132 (kh stride 528) = 1056
#define W_OFF     5152     // w i8 (x127): 128 B + Sw (int) @ +128
#define ZP_OFF    5408     // 16 B zero page (bf16 epilogue pad cols)
#define XST_OFF   5424     // 104 chunks x 16 B bf16 (encoder prologue only)
#define T2L_OFF   7104     // T2 i4 ct 0..31: 64 frag-pairs x 1024 B = 65536
#define RED_OFF   7104     // epilogue overlay (T2L dead by then): 16 KiB
#define LDS_BYTES 72640    // ~70.9 KiB -> 2 blocks/CU (<= 80 KiB each)

__global__
__attribute__((amdgpu_flat_work_group_size(1024, 1024), amdgpu_waves_per_eu(4, 8)))
void phasenn_kernel(
    const float* __restrict__ x, const float* __restrict__ W_enc,
    const float* __restrict__ b_enc, const float* __restrict__ xi,
    const float* __restrict__ W_out, const float* __restrict__ b_out,
    float* __restrict__ dout, char* __restrict__ wsb, TCons tc)
{
  __shared__ __align__(16) char smem[LDS_BYTES];

  const int tid  = threadIdx.x;
  const int bk   = blockIdx.x;        // batch row bk
  const int w    = tid >> 6;          // 16 waves
  const int lane = tid & 63;
  const int q    = lane >> 4;
  const int b16  = lane & 15;         // MFMA col slot (batch row duplicated x16)
  const int j4   = b16 >> 2;          // lane's n-subtile j / GEMM2 ct select
  const int r4   = b16 & 3;           // lane's r within the D reg quad
  const int nph  = (w*4 + j4)*16 + q*4 + r4;   // the ONE phase this lane owns

  char* T1g = wsb;                    // 64 KiB: (pt 8, F 16) i2 frag-pairs x 64 lanes x 8 B
  char* T2g = wsb + (256 << 10);      // i4 frag-pairs (ct*2+P2)*1024, ct>=32 used

  // ---- LDS init: zero page only
  if (tid < 4) *(unsigned*)(smem + ZP_OFF + tid*4) = 0;

  // ---- xstage: x row bk -> bf16 B-frag chunks (linear), d>=784 zero (encoder)
  if (tid < 100) {
    const int dg = tid;
    bf16x8 fr = {0,0,0,0,0,0,0,0};
    if (dg < 98) {
      f32x4 v0 = *(const f32x4*)(x + (size_t)bk*784 + dg*8);
      f32x4 v1 = *(const f32x4*)(x + (size_t)bk*784 + dg*8 + 4);
      #pragma unroll
      for (int i = 0; i < 8; ++i) fr[i] = (short)f2bf(i < 4 ? v0[i] : v1[i-4]);
    }
    *(bf16x8*)(smem + XST_OFF + (dg << 4)) = fr;
  }

  // ---- table gen
  if (w < 8) {  // T1 i2 -> global: lane: p = w*16+b16, n = F*64 + q*16 + i
    const int p = w*16 + b16;
    for (int F = 0; F < 16; ++F) {
      const int n0 = F*64 + q*16;
      f32x4 v0 = *(const f32x4*)(xi + p*1024 + n0);
      f32x4 v1 = *(const f32x4*)(xi + p*1024 + n0 + 4);
      f32x4 v2 = *(const f32x4*)(xi + p*1024 + n0 + 8);
      f32x4 v3 = *(const f32x4*)(xi + p*1024 + n0 + 12);
      unsigned pc = 0, ps = 0;
      #pragma unroll
      for (int i = 0; i < 16; ++i) {
        float xv = (i < 4) ? v0[i] : (i < 8) ? v1[i-4] : (i < 12) ? v2[i-8] : v3[i-12];
        int uc = __float2int_rn(__cosf(xv)*1.5f + 1.5f);   // 0..3
        int us = __float2int_rn(__sinf(xv)*1.5f + 1.5f);
        const int sh = 8*(i & 3) + 2*(i >> 2);
        pc |= (unsigned)uc << sh;
        ps |= (unsigned)us << sh;
      }
      i32x2 P = {(int)pc, (int)ps};
      *(i32x2*)(T1g + (size_t)(w*16 + F)*512 + lane*8) = P;
    }
  } else {      // T2 i4: ct<32 -> LDS, ct>=32 -> global.  lane: n = ct*16+b16
    const int w2 = w - 8;
    for (int f = 0; f < 16; ++f) {
      const int ct = w2*8 + (f >> 1), P2 = f & 1;
      const int n = ct*16 + b16;
      int cu[16], su[16];
      #pragma unroll
      for (int i = 0; i < 16; ++i) {
        float xv = xi[(P2*64 + q*16 + i)*1024 + n];
        su[i] = __float2int_rn(__sinf(xv)*7.0f) + 8;   // 1..15
        cu[i] = __float2int_rn(__cosf(xv)*7.0f) + 8;
      }
      unsigned pc0=0, pc1=0, ps0=0, ps1=0;
      #pragma unroll
      for (int i = 0; i < 4; ++i) {
        pc0 |= (unsigned)(cu[i]     | (cu[i+4]  << 4)) << (8*i);
        pc1 |= (unsigned)(cu[8+i]   | (cu[12+i] << 4)) << (8*i);
        ps0 |= (unsigned)(su[i]     | (su[i+4]  << 4)) << (8*i);
        ps1 |= (unsigned)(su[8+i]   | (su[12+i] << 4)) << (8*i);
      }
      i32x4 P = {(int)pc0, (int)pc1, (int)ps0, (int)ps1};
      char* dst = (ct < 32)
          ? (smem + T2L_OFF + (size_t)(ct*2 + P2)*1024 + lane*16)
          : (T2g + (size_t)(ct*2 + P2)*1024 + lane*16);
      *(i32x4*)(dst) = P;
    }
  }
  __syncthreads();

  // ---- encoder (bf16 MFMA): B cols all duplicate row bk; lane keeps 1 phase.
  float p0, ka, pwv;
  {
    f32x4 pac[4] = {{0,0,0,0},{0,0,0,0},{0,0,0,0},{0,0,0,0}};
    for (int kt = 0; kt < 25; ++kt) {
      bf16x8 bfr = *(const bf16x8*)(smem + XST_OFF + ((kt*4 + q) << 4));
      const int d = kt*32 + q*8;
      #pragma unroll
      for (int j = 0; j < 4; ++j) {
        bf16x8 afr = {0,0,0,0,0,0,0,0};
        if (d < 784) {
          const int n = (w*4 + j)*16 + b16;
          f32x4 v0 = *(const f32x4*)(W_enc + n*784 + d);
          f32x4 v1 = *(const f32x4*)(W_enc + n*784 + d + 4);
          #pragma unroll
          for (int i = 0; i < 8; ++i) afr[i] = (short)f2bf(i < 4 ? v0[i] : v1[i-4]);
        }
        pac[j] = __builtin_amdgcn_mfma_f32_16x16x32_bf16(afr, bfr, pac[j], 0, 0, 0);
      }
    }
    f32x4 pc = (j4==0) ? pac[0] : (j4==1) ? pac[1] : (j4==2) ? pac[2] : pac[3];
    float vA = (r4==0) ? pc[0] : (r4==1) ? pc[1] : (r4==2) ? pc[2] : pc[3];
    float ph = 6.283185307179586f / (1.0f + __expf(-(vA + b_enc[nph])));
    p0 = ph; pwv = ph; ka = 0.0f;
  }

  const float dtf = 0.03125f, half = 0.015625f;
  const float sixth = (float)(0.03125/6.0);
  const float mscale = (float)(2.0 / (1024.0 * 190.5));     // BETA/N / (1.5*127)
  const float kscale = (float)(1.0 / 889.0);                // 1/(7*127)

  char* a1wr = smem + A1_OFF + nph;   // per-lane feat byte address (constant)

  for (int e = 0; e < 64; ++e) {
    float csv, snv;
    // ---- Phase A: all 64 lanes, 1 phase each; 1 cos + 1 sin byte store
    {
      snv = __sinf(pwv);
      csv = __cosf(pwv);
      *(char*)(a1wr)        = (char)(__float2int_rn(csv*127.0f));
      *(char*)(a1wr + 1024) = (char)(__float2int_rn(snv*127.0f));
    }
    __syncthreads();

    // ---- GEMM1 i8 K=64 with i2 T1 (SWAR unpack, biased +1.5); 16 MFMA/wave
    {
      const int pt = w & 7, kh = w >> 3;
      i32x4 accC = {0,0,0,0}, accS = {0,0,0,0};
      const char* t1b = T1g + (size_t)(pt*16 + kh*8)*512 + lane*8;
      const char* a1b = smem + A1_OFF + kh*512 + q*16;
      const unsigned M2 = 0x03030303u;
      #pragma unroll
      for (int i2 = 0; i2 < 8; ++i2) {
        i32x2 pk = *(const i32x2*)(t1b + (size_t)i2*512);
        unsigned pc = (unsigned)pk[0], ps = (unsigned)pk[1];
        i32x4 ca = { (int)(pc & M2), (int)((pc >> 2) & M2),
                     (int)((pc >> 4) & M2), (int)((pc >> 6) & M2) };
        i32x4 sa = { (int)(ps & M2), (int)((ps >> 2) & M2),
                     (int)((ps >> 4) & M2), (int)((ps >> 6) & M2) };
        i32x4 bc = *(const i32x4*)(a1b + i2*64);
        i32x4 bs = *(const i32x4*)(a1b + i2*64 + 1024);
        accC = __builtin_amdgcn_mfma_i32_16x16x64_i8(ca, bc, accC, 0, 0, 0);
        accS = __builtin_amdgcn_mfma_i32_16x16x64_i8(sa, bs, accS, 0, 0, 0);
      }
      if (b16 == 0) {
        i32x4 acc = accC + accS;
        *(i32x4*)(smem + MBUF_OFF + kh*528 + ((pt*16 + q*4) << 2)) = acc;
      }
    }
    __syncthreads();

    // ---- softmax (wave 0): shift-invariant to T1 bias; w i8 (x127) + exact
    // integer Sw = Sum_p w^i8_p for GEMM2 bias correction.
    if (w == 0) {
      const char* mb = smem + MBUF_OFF + lane*8;
      int a0 = *(const int*)(mb),       a1 = *(const int*)(mb + 4);
      int b0 = *(const int*)(mb + 528), b1 = *(const int*)(mb + 528 + 4);
      float e0 = __expf((float)(a0 + b0) * mscale);
      float e1 = __expf((float)(a1 + b1) * mscale);
      float s = e0 + e1;
      #pragma unroll
      for (int off = 1; off < 64; off <<= 1) s += __shfl_xor(s, off, 64);
      const float inv = 127.0f / s;
      int w0 = __float2int_rn(e0 * inv);
      int w1 = __float2int_rn(e1 * inv);
      *(unsigned short*)(smem + W_OFF + lane*2) =
          (unsigned short)((w0 & 255) | (w1 << 8));
      int sw = w0 + w1;
      #pragma unroll
      for (int off = 1; off < 64; off <<= 1) sw += __shfl_xor(sw, off, 64);
      if (lane == 0) *(int*)(smem + W_OFF + 128) = sw;
    }
    __syncthreads();

    // ---- GEMM2 (i4 T2: waves 0..7 LDS, 8..15 global) + RK4: 16 MFMA/wave;
    // bias 8*Sw subtracted exactly; cached trig.
    {
      const float swt = tc.s[e], cwt = tc.c[e];
      const int st = e & 3;
      i32x4 wf0 = *(const i32x4*)(smem + W_OFF + q*16);
      i32x4 wf1 = *(const i32x4*)(smem + W_OFF + 64 + q*16);
      const int bias8 = 8 * (*(const int*)(smem + W_OFF + 128));
      i32x4 aC[4] = {{0,0,0,0},{0,0,0,0},{0,0,0,0},{0,0,0,0}};
      i32x4 aS[4] = {{0,0,0,0},{0,0,0,0},{0,0,0,0},{0,0,0,0}};
      const unsigned M = 0x0F0F0F0Fu;
      if (w < 8) {
        const char* t2b = smem + T2L_OFF + (size_t)(w*8)*1024 + lane*16;
        #pragma unroll
        for (int c = 0; c < 4; ++c)
          #pragma unroll
          for (int P2 = 0; P2 < 2; ++P2) {
            i32x4 pk = *(const i32x4*)(t2b + (size_t)(c*2 + P2)*1024);
            i32x4 ct_ = { (int)((unsigned)pk[0] & M), (int)(((unsigned)pk[0] >> 4) & M),
                          (int)((unsigned)pk[1] & M), (int)(((unsigned)pk[1] >> 4) & M) };
            i32x4 st_ = { (int)((unsigned)pk[2] & M), (int)(((unsigned)pk[2] >> 4) & M),
                          (int)((unsigned)pk[3] & M), (int)(((unsigned)pk[3] >> 4) & M) };
            i32x4 wf = P2 ? wf1 : wf0;
            aC[c] = __builtin_amdgcn_mfma_i32_16x16x64_i8(ct_, wf, aC[c], 0, 0, 0);
            aS[c] = __builtin_amdgcn_mfma_i32_16x16x64_i8(st_, wf, aS[c], 0, 0, 0);
          }
      } else {
        const char* t2b = T2g + (size_t)(w*8)*1024 + lane*16;
        #pragma unroll
        for (int c = 0; c < 4; ++c)
          #pragma unroll
          for (int P2 = 0; P2 < 2; ++P2) {
            i32x4 pk = *(const i32x4*)(t2b + (size_t)(c*2 + P2)*1024);
            i32x4 ct_ = { (int)((unsigned)pk[0] & M), (int)(((unsigned)pk[0] >> 4) & M),
                          (int)((unsigned)pk[1] & M), (int)(((unsigned)pk[1] >> 4) & M) };
            i32x4 st_ = { (int)((unsigned)pk[2] & M), (int)(((unsigned)pk[2] >> 4) & M),
                          (int)((unsigned)pk[3] & M), (int)(((unsigned)pk[3] >> 4) & M) };
            i32x4 wf = P2 ? wf1 : wf0;
            aC[c] = __builtin_amdgcn_mfma_i32_16x16x64_i8(ct_, wf, aC[c], 0, 0, 0);
            aS[c] = __builtin_amdgcn_mfma_i32_16x16x64_i8(st_, wf, aS[c], 0, 0, 0);
          }
      }
      i32x4 c4 = (j4==0) ? aC[0] : (j4==1) ? aC[1] : (j4==2) ? aC[2] : aC[3];
      i32x4 s4 = (j4==0) ? aS[0] : (j4==1) ? aS[1] : (j4==2) ? aS[2] : aS[3];
      int iC = (r4==0) ? c4[0] : (r4==1) ? c4[1] : (r4==2) ? c4[2] : c4[3];
      int iS = (r4==0) ? s4[0] : (r4==1) ? s4[1] : (r4==2) ? s4[2] : s4[3];
      float vC = (float)(iC - bias8);
      float vS = (float)(iS - bias8);
      float kv = (snv*vC - csv*vS) * kscale
               + 0.08f*(swt*csv - cwt*snv);           // A*sin(wt - phi)
      if (st == 0)      { ka  = kv;           pwv = p0 + kv*half; }
      else if (st == 1) { ka += 2.0f*kv;      pwv = p0 + kv*half; }
      else if (st == 2) { ka += 2.0f*kv;      pwv = p0 + kv*dtf;  }
      else { ka += kv; p0 += ka*sixth; pwv = p0; }
    }
  }

  // ---- epilogue (bf16 MFMA): out = [cos phiT, sin phiT] @ W_out^T + b_out
  __syncthreads();
  {
    *(unsigned short*)(smem + A1_OFF + nph*2)        = f2bf(__cosf(p0));
    *(unsigned short*)(smem + A1_OFF + 2048 + nph*2) = f2bf(__sinf(p0));
  }
  __syncthreads();
  {  // D[cl][col] partial over this wave's 4 ktiles; A = W_out rows (cl<10, pad 0)
    f32x4 acc = {0.f, 0.f, 0.f, 0.f};
    #pragma unroll
    for (int i2 = 0; i2 < 4; ++i2) {
      const int kt = w*4 + i2;
      const int k = kt*32 + q*8;
      bf16x8 afr = {0,0,0,0,0,0,0,0};
      if (b16 < 10) {
        f32x4 v0 = *(const f32x4*)(W_out + b16*2048 + k);
        f32x4 v1 = *(const f32x4*)(W_out + b16*2048 + k + 4);
        #pragma unroll
        for (int i = 0; i < 8; ++i) afr[i] = (short)f2bf(i < 4 ? v0[i] : v1[i-4]);
      }
      const char* baddr = (b16 == 0)
          ? (smem + A1_OFF + ((kt*4 + q) << 4))
          : (smem + ZP_OFF);
      bf16x8 bfr = *(const bf16x8*)baddr;
      acc = __builtin_amdgcn_mfma_f32_16x16x32_bf16(afr, bfr, acc, 0, 0, 0);
    }
    *(f32x4*)(smem + RED_OFF + ((w*64 + lane) << 4)) = acc;
  }
  __syncthreads();
  if (tid < 64) {   // reduce 16 wave-partials; lane: col = tid&15, cl = (tid>>4)*4+r
    f32x4 s = {0.f, 0.f, 0.f, 0.f};
    #pragma unroll
    for (int w2 = 0; w2 < 16; ++w2)
      s += *(const f32x4*)(smem + RED_OFF + ((w2*64 + tid) << 4));
    const int b = tid & 15, q2 = tid >> 4;
    if (b == 0) {
      #pragma unroll
      for (int r = 0; r < 4; ++r) {
        const int cl = q2*4 + r;
        if (cl < 10)
          dout[(size_t)bk*10 + cl] = s[r] + b_out[cl];
      }
    }
  }
}

extern "C" void kernel_launch(void* const* d_in, const int* in_sizes, int n_in,
                              void* d_out, int out_size, void* d_ws, size_t ws_size,
                              hipStream_t stream) {
  (void)in_sizes; (void)n_in; (void)ws_size; (void)out_size;
  const float* x     = (const float*)d_in[0];
  const float* W_enc = (const float*)d_in[1];
  const float* b_enc = (const float*)d_in[2];
  const float* xi    = (const float*)d_in[3];
  const float* W_out = (const float*)d_in[4];
  const float* b_out = (const float*)d_in[5];
  float* out = (float*)d_out;
  char* wsb = (char*)d_ws;   // T1 i2 64K @0 | T2 i4 (ct>=32) @256K; rewritten per launch

  TCons tc;
  const double OME = 2.0 * 3.14159265358979323846 * 200.0;
  const double dtd = 0.03125;
  const double co[4] = {0.0, 0.5, 0.5, 1.0};
  for (int e = 0; e < 64; ++e) {
    double t = ((double)(e >> 2) + co[e & 3]) * dtd;
    tc.s[e] = (float)sin(OME * t);
    tc.c[e] = (float)cos(OME * t);
  }

  phasenn_kernel<<<dim3(256), dim3(1024), 0, stream>>>(
      x, W_enc, b_enc, xi, W_out, b_out, out, wsb, tc);
}

// Round 19
// 362.218 us; speedup vs baseline: 1.0140x; 1.0140x over previous
//
#include <hip/hip_runtime.h>
#include <math.h>

// PhaseNN on MI355X.  ROUND 30 = ROUND 29 resubmitted (container infra failure,
// no kernel signal -- same signature as R13's infra failure, which ran clean on
// resubmit).  T1 i2 + T2 i8-split (untested best-of-both cell).
// Plateau 2x2 from measured data:  R23 (T1 i4 + T2 i8-split, no GEMM2 unpack)
// = 348.7 best-harness; R25/R27 (T1 i2 + T2 i4-LDS, 16-wave unpack) ~ 355/361.
// R23<->R24 measured the stream<->unpack swap at ~+8 us for unpack; R24->R25
// measured T1 i4->i2 at -5-8 us.  R29/R30 takes the better side of both:
//  - T1 i2 global (64 KB/eval stream, SWAR unpack in GEMM1 only);
//  - T2 i8: ct<36 LDS (147K) / ct>=36 global (112 KB/eval, waves 9..15);
//    GEMM2 reads signed i8 directly: NO unpack, NO bias8/Sw machinery;
//    kscale = 1/127^2.  T2 i8 also more accurate than i4.
// absmax expected 0.015625.  Tripwire: WRITE > 4 MB = spill -> revert.
// If this lands within noise of 348: structure is at its latency floor
// (no pipe > 60%, occupancy geometry-capped at 16/32, barriers irreducible).
// Structure: 256 blocks x 1 row, 16 waves, i8-MFMA K=64, 3 barriers/eval.

typedef __attribute__((ext_vector_type(4))) float f32x4;
typedef __attribute__((ext_vector_type(4))) int   i32x4;
typedef __attribute__((ext_vector_type(2))) int   i32x2;
typedef __attribute__((ext_vector_type(8))) short bf16x8;

struct TCons { float s[64]; float c[64]; };

__device__ __forceinline__ unsigned short f2bf(float f) {
  unsigned u = __builtin_bit_cast(unsigned, f);
  return (unsigned short)((u + 0x7FFFu + ((u >> 16) & 1u)) >> 16);
}
// pack 4 floats (|v|<=1) -> 4 i8 bytes scaled x127, LSB first
__device__ __forceinline__ int pk4i8(const float* v) {
  int a = __float2int_rn(v[0]*127.0f) & 255;
  int b = __float2int_rn(v[1]*127.0f) & 255;
  int c = __float2int_rn(v[2]*127.0f) & 255;
  int d = __float2int_rn(v[3]*127.0f);
  return a | (b << 8) | (c << 16) | (d << 24);
}

#define A1_OFF    0        // feats: GEMM1 i8 [cos 1024 | sin 1024]; epilogue bf16 [cos 2048 | sin 2048]
#define MBUF_OFF  4096     // m partials i32: 2 kh x 132 (kh stride 528) = 1056
#define W_OFF     5152     // w i8 (x127): 128 B
#define ZP_OFF    5408     // 16 B zero page (bf16 epilogue pad cols)
#define XST_OFF   5424     // 104 chunks x 16 B bf16 (encoder prologue only)
#define T2L_OFF   7104     // T2 i8 ct 0..35: 72 frag-pairs x 2048 B = 147456
#define RED_OFF   7104     // epilogue overlay (T2L dead by then): 16 KiB
#define LDS_BYTES 154560   // ~151 KiB of 160 KiB

__global__
__attribute__((amdgpu_flat_work_group_size(1024, 1024), amdgpu_waves_per_eu(4, 4)))
void phasenn_kernel(
    const float* __restrict__ x, const float* __restrict__ W_enc,
    const float* __restrict__ b_enc, const float* __restrict__ xi,
    const float* __restrict__ W_out, const float* __restrict__ b_out,
    float* __restrict__ dout, char* __restrict__ wsb, TCons tc)
{
  __shared__ __align__(16) char smem[LDS_BYTES];

  const int tid  = threadIdx.x;
  const int bk   = blockIdx.x;        // batch row bk
  const int w    = tid >> 6;          // 16 waves
  const int lane = tid & 63;
  const int q    = lane >> 4;
  const int b16  = lane & 15;         // MFMA col slot (batch row duplicated x16)
  const int j4   = b16 >> 2;          // lane's n-subtile j / GEMM2 ct select
  const int r4   = b16 & 3;           // lane's r within the D reg quad
  const int nph  = (w*4 + j4)*16 + q*4 + r4;   // the ONE phase this lane owns

  char* T1g = wsb;                    // 64 KiB: (pt 8, F 16) i2 frag-pairs x 64 lanes x 8 B
  char* T2g = wsb + (256 << 10);      // i8 frag-pairs (ct*2+P2)*2048, ct>=36 used

  // ---- LDS init: zero page only
  if (tid < 4) *(unsigned*)(smem + ZP_OFF + tid*4) = 0;

  // ---- xstage: x row bk -> bf16 B-frag chunks (linear), d>=784 zero (encoder)
  if (tid < 100) {
    const int dg = tid;
    bf16x8 fr = {0,0,0,0,0,0,0,0};
    if (dg < 98) {
      f32x4 v0 = *(const f32x4*)(x + (size_t)bk*784 + dg*8);
      f32x4 v1 = *(const f32x4*)(x + (size_t)bk*784 + dg*8 + 4);
      #pragma unroll
      for (int i = 0; i < 8; ++i) fr[i] = (short)f2bf(i < 4 ? v0[i] : v1[i-4]);
    }
    *(bf16x8*)(smem + XST_OFF + (dg << 4)) = fr;
  }

  // ---- table gen
  if (w < 8) {  // T1 i2 -> global: lane: p = w*16+b16, n = F*64 + q*16 + i
    const int p = w*16 + b16;
    for (int F = 0; F < 16; ++F) {
      const int n0 = F*64 + q*16;
      f32x4 v0 = *(const f32x4*)(xi + p*1024 + n0);
      f32x4 v1 = *(const f32x4*)(xi + p*1024 + n0 + 4);
      f32x4 v2 = *(const f32x4*)(xi + p*1024 + n0 + 8);
      f32x4 v3 = *(const f32x4*)(xi + p*1024 + n0 + 12);
      unsigned pc = 0, ps = 0;
      #pragma unroll
      for (int i = 0; i < 16; ++i) {
        float xv = (i < 4) ? v0[i] : (i < 8) ? v1[i-4] : (i < 12) ? v2[i-8] : v3[i-12];
        int uc = __float2int_rn(__cosf(xv)*1.5f + 1.5f);   // 0..3
        int us = __float2int_rn(__sinf(xv)*1.5f + 1.5f);
        const int sh = 8*(i & 3) + 2*(i >> 2);
        pc |= (unsigned)uc << sh;
        ps |= (unsigned)us << sh;
      }
      i32x2 P = {(int)pc, (int)ps};
      *(i32x2*)(T1g + (size_t)(w*16 + F)*512 + lane*8) = P;
    }
  } else {      // T2 i8: ct<36 -> LDS, ct>=36 -> global.  lane: n = ct*16+b16
    const int w2 = w - 8;
    for (int f = 0; f < 16; ++f) {
      const int ct = w2*8 + (f >> 1), P2 = f & 1;
      const int n = ct*16 + b16;
      float cv[16], sv[16];
      #pragma unroll
      for (int i = 0; i < 16; ++i) {
        float xv = xi[(P2*64 + q*16 + i)*1024 + n];
        sv[i] = __sinf(xv); cv[i] = __cosf(xv);
      }
      i32x4 C = { pk4i8(cv), pk4i8(cv+4), pk4i8(cv+8), pk4i8(cv+12) };
      i32x4 S = { pk4i8(sv), pk4i8(sv+4), pk4i8(sv+8), pk4i8(sv+12) };
      char* dst = (ct < 36)
          ? (smem + T2L_OFF + (size_t)(ct*2 + P2)*2048 + lane*16)
          : (T2g + (size_t)(ct*2 + P2)*2048 + lane*16);
      *(i32x4*)(dst) = C; *(i32x4*)(dst + 1024) = S;
    }
  }
  __syncthreads();

  // ---- encoder (bf16 MFMA): B cols all duplicate row bk; lane keeps 1 phase.
  float p0, ka, pwv;
  {
    f32x4 pac[4] = {{0,0,0,0},{0,0,0,0},{0,0,0,0},{0,0,0,0}};
    for (int kt = 0; kt < 25; ++kt) {
      bf16x8 bfr = *(const bf16x8*)(smem + XST_OFF + ((kt*4 + q) << 4));
      const int d = kt*32 + q*8;
      #pragma unroll
      for (int j = 0; j < 4; ++j) {
        bf16x8 afr = {0,0,0,0,0,0,0,0};
        if (d < 784) {
          const int n = (w*4 + j)*16 + b16;
          f32x4 v0 = *(const f32x4*)(W_enc + n*784 + d);
          f32x4 v1 = *(const f32x4*)(W_enc + n*784 + d + 4);
          #pragma unroll
          for (int i = 0; i < 8; ++i) afr[i] = (short)f2bf(i < 4 ? v0[i] : v1[i-4]);
        }
        pac[j] = __builtin_amdgcn_mfma_f32_16x16x32_bf16(afr, bfr, pac[j], 0, 0, 0);
      }
    }
    f32x4 pc = (j4==0) ? pac[0] : (j4==1) ? pac[1] : (j4==2) ? pac[2] : pac[3];
    float vA = (r4==0) ? pc[0] : (r4==1) ? pc[1] : (r4==2) ? pc[2] : pc[3];
    float ph = 6.283185307179586f / (1.0f + __expf(-(vA + b_enc[nph])));
    p0 = ph; pwv = ph; ka = 0.0f;
  }

  const float dtf = 0.03125f, half = 0.015625f;
  const float sixth = (float)(0.03125/6.0);
  const float mscale = (float)(2.0 / (1024.0 * 190.5));     // BETA/N / (1.5*127)
  const float kscale = (float)(1.0 / 16129.0);              // 1/127^2

  char* a1wr = smem + A1_OFF + nph;   // per-lane feat byte address (constant)

  for (int e = 0; e < 64; ++e) {
    float csv, snv;
    // ---- Phase A: all 64 lanes, 1 phase each; 1 cos + 1 sin byte store
    {
      snv = __sinf(pwv);
      csv = __cosf(pwv);
      *(char*)(a1wr)        = (char)(__float2int_rn(csv*127.0f));
      *(char*)(a1wr + 1024) = (char)(__float2int_rn(snv*127.0f));
    }
    __syncthreads();

    // ---- GEMM1 i8 K=64 with i2 T1 (SWAR unpack, biased +1.5); 16 MFMA/wave
    {
      const int pt = w & 7, kh = w >> 3;
      i32x4 accC = {0,0,0,0}, accS = {0,0,0,0};
      const char* t1b = T1g + (size_t)(pt*16 + kh*8)*512 + lane*8;
      const char* a1b = smem + A1_OFF + kh*512 + q*16;
      const unsigned M2 = 0x03030303u;
      #pragma unroll
      for (int i2 = 0; i2 < 8; ++i2) {
        i32x2 pk = *(const i32x2*)(t1b + (size_t)i2*512);
        unsigned pc = (unsigned)pk[0], ps = (unsigned)pk[1];
        i32x4 ca = { (int)(pc & M2), (int)((pc >> 2) & M2),
                     (int)((pc >> 4) & M2), (int)((pc >> 6) & M2) };
        i32x4 sa = { (int)(ps & M2), (int)((ps >> 2) & M2),
                     (int)((ps >> 4) & M2), (int)((ps >> 6) & M2) };
        i32x4 bc = *(const i32x4*)(a1b + i2*64);
        i32x4 bs = *(const i32x4*)(a1b + i2*64 + 1024);
        accC = __builtin_amdgcn_mfma_i32_16x16x64_i8(ca, bc, accC, 0, 0, 0);
        accS = __builtin_amdgcn_mfma_i32_16x16x64_i8(sa, bs, accS, 0, 0, 0);
      }
      if (b16 == 0) {
        i32x4 acc = accC + accS;
        *(i32x4*)(smem + MBUF_OFF + kh*528 + ((pt*16 + q*4) << 2)) = acc;
      }
    }
    __syncthreads();

    // ---- softmax (wave 0): shift-invariant to T1 bias; w i8 (x127)
    if (w == 0) {
      const char* mb = smem + MBUF_OFF + lane*8;
      int a0 = *(const int*)(mb),       a1 = *(const int*)(mb + 4);
      int b0 = *(const int*)(mb + 528), b1 = *(const int*)(mb + 528 + 4);
      float e0 = __expf((float)(a0 + b0) * mscale);
      float e1 = __expf((float)(a1 + b1) * mscale);
      float s = e0 + e1;
      #pragma unroll
      for (int off = 1; off < 64; off <<= 1) s += __shfl_xor(s, off, 64);
      const float inv = 127.0f / s;
      int w0 = __float2int_rn(e0 * inv);
      int w1 = __float2int_rn(e1 * inv);
      *(unsigned short*)(smem + W_OFF + lane*2) =
          (unsigned short)((w0 & 255) | (w1 << 8));
    }
    __syncthreads();

    // ---- GEMM2 i8 (T2 signed i8: waves 0..8 LDS, 9..15 global; NO unpack,
    // NO bias) + RK4: 16 MFMA/wave; cached trig.
    {
      const float swt = tc.s[e], cwt = tc.c[e];
      const int st = e & 3;
      i32x4 wf0 = *(const i32x4*)(smem + W_OFF + q*16);
      i32x4 wf1 = *(const i32x4*)(smem + W_OFF + 64 + q*16);
      i32x4 aC[4] = {{0,0,0,0},{0,0,0,0},{0,0,0,0},{0,0,0,0}};
      i32x4 aS[4] = {{0,0,0,0},{0,0,0,0},{0,0,0,0},{0,0,0,0}};
      if (w < 9) {
        const char* t2b = smem + T2L_OFF + (size_t)(w*8)*2048 + lane*16;
        #pragma unroll
        for (int c = 0; c < 4; ++c)
          #pragma unroll
          for (int P2 = 0; P2 < 2; ++P2) {
            i32x4 ct_ = *(const i32x4*)(t2b + (size_t)(c*2 + P2)*2048);
            i32x4 st_ = *(const i32x4*)(t2b + (size_t)(c*2 + P2)*2048 + 1024);
            i32x4 wf = P2 ? wf1 : wf0;
            aC[c] = __builtin_amdgcn_mfma_i32_16x16x64_i8(ct_, wf, aC[c], 0, 0, 0);
            aS[c] = __builtin_amdgcn_mfma_i32_16x16x64_i8(st_, wf, aS[c], 0, 0, 0);
          }
      } else {
        const char* t2b = T2g + (size_t)(w*8)*2048 + lane*16;
        #pragma unroll
        for (int c = 0; c < 4; ++c)
          #pragma unroll
          for (int P2 = 0; P2 < 2; ++P2) {
            i32x4 ct_ = *(const i32x4*)(t2b + (size_t)(c*2 + P2)*2048);
            i32x4 st_ = *(const i32x4*)(t2b + (size_t)(c*2 + P2)*2048 + 1024);
            i32x4 wf = P2 ? wf1 : wf0;
            aC[c] = __builtin_amdgcn_mfma_i32_16x16x64_i8(ct_, wf, aC[c], 0, 0, 0);
            aS[c] = __builtin_amdgcn_mfma_i32_16x16x64_i8(st_, wf, aS[c], 0, 0, 0);
          }
      }
      i32x4 c4 = (j4==0) ? aC[0] : (j4==1) ? aC[1] : (j4==2) ? aC[2] : aC[3];
      i32x4 s4 = (j4==0) ? aS[0] : (j4==1) ? aS[1] : (j4==2) ? aS[2] : aS[3];
      int iC = (r4==0) ? c4[0] : (r4==1) ? c4[1] : (r4==2) ? c4[2] : c4[3];
      int iS = (r4==0) ? s4[0] : (r4==1) ? s4[1] : (r4==2) ? s4[2] : s4[3];
      float vC = (float)iC;
      float vS = (float)iS;
      float kv = (snv*vC - csv*vS) * kscale
               + 0.08f*(swt*csv - cwt*snv);           // A*sin(wt - phi)
      if (st == 0)      { ka  = kv;           pwv = p0 + kv*half; }
      else if (st == 1) { ka += 2.0f*kv;      pwv = p0 + kv*half; }
      else if (st == 2) { ka += 2.0f*kv;      pwv = p0 + kv*dtf;  }
      else { ka += kv; p0 += ka*sixth; pwv = p0; }
    }
  }

  // ---- epilogue (bf16 MFMA): out = [cos phiT, sin phiT] @ W_out^T + b_out
  __syncthreads();
  {
    *(unsigned short*)(smem + A1_OFF + nph*2)        = f2bf(__cosf(p0));
    *(unsigned short*)(smem + A1_OFF + 2048 + nph*2) = f2bf(__sinf(p0));
  }
  __syncthreads();
  {  // D[cl][col] partial over this wave's 4 ktiles; A = W_out rows (cl<10, pad 0)
    f32x4 acc = {0.f, 0.f, 0.f, 0.f};
    #pragma unroll
    for (int i2 = 0; i2 < 4; ++i2) {
      const int kt = w*4 + i2;
      const int k = kt*32 + q*8;
      bf16x8 afr = {0,0,0,0,0,0,0,0};
      if (b16 < 10) {
        f32x4 v0 = *(const f32x4*)(W_out + b16*2048 + k);
        f32x4 v1 = *(const f32x4*)(W_out + b16*2048 + k + 4);
        #pragma unroll
        for (int i = 0; i < 8; ++i) afr[i] = (short)f2bf(i < 4 ? v0[i] : v1[i-4]);
      }
      const char* baddr = (b16 == 0)
          ? (smem + A1_OFF + ((kt*4 + q) << 4))
          : (smem + ZP_OFF);
      bf16x8 bfr = *(const bf16x8*)baddr;
      acc = __builtin_amdgcn_mfma_f32_16x16x32_bf16(afr, bfr, acc, 0, 0, 0);
    }
    *(f32x4*)(smem + RED_OFF + ((w*64 + lane) << 4)) = acc;
  }
  __syncthreads();
  if (tid < 64) {   // reduce 16 wave-partials; lane: col = tid&15, cl = (tid>>4)*4+r
    f32x4 s = {0.f, 0.f, 0.f, 0.f};
    #pragma unroll
    for (int w2 = 0; w2 < 16; ++w2)
      s += *(const f32x4*)(smem + RED_OFF + ((w2*64 + tid) << 4));
    const int b = tid & 15, q2 = tid >> 4;
    if (b == 0) {
      #pragma unroll
      for (int r = 0; r < 4; ++r) {
        const int cl = q2*4 + r;
        if (cl < 10)
          dout[(size_t)bk*10 + cl] = s[r] + b_out[cl];
      }
    }
  }
}

extern "C" void kernel_launch(void* const* d_in, const int* in_sizes, int n_in,
                              void* d_out, int out_size, void* d_ws, size_t ws_size,
                              hipStream_t stream) {
  (void)in_sizes; (void)n_in; (void)ws_size; (void)out_size;
  const float* x     = (const float*)d_in[0];
  const float* W_enc = (const float*)d_in[1];
  const float* b_enc = (const float*)d_in[2];
  const float* xi    = (const float*)d_in[3];
  const float* W_out = (const float*)d_in[4];
  const float* b_out = (const float*)d_in[5];
  float* out = (float*)d_out;
  char* wsb = (char*)d_ws;   // T1 i2 64K @0 | T2 i8 (ct>=36) @256K; rewritten per launch

  TCons tc;
  const double OME = 2.0 * 3.14159265358979323846 * 200.0;
  const double dtd = 0.03125;
  const double co[4] = {0.0, 0.5, 0.5, 1.0};
  for (int e = 0; e < 64; ++e) {
    double t = ((double)(e >> 2) + co[e & 3]) * dtd;
    tc.s[e] = (float)sin(OME * t);
    tc.c[e] = (float)cos(OME * t);
  }

  phasenn_kernel<<<dim3(256), dim3(1024), 0, stream>>>(
      x, W_enc, b_enc, xi, W_out, b_out, out, wsb, tc);
}

// Round 20
// 347.325 us; speedup vs baseline: 1.0574x; 1.0429x over previous
//
#include <hip/hip_runtime.h>
#include <math.h>

// PhaseNN on MI355X.  ROUND 31 = ROUND 23 resubmitted as FINAL (best harness
// result of the session: 348.7 us).
// Plateau evidence (R23-R30): all four table-precision cells land 348-362 us
// (harness noise +-10-15); R30 removed 13 points of VALUBusy with ZERO wall
// change -> no pipe is binding.  Structural floor: serial chain
// PhaseA -> GEMM1 -> softmax -> GEMM2 -> RK4 x 64 evals x 3 barriers, with
// occupancy geometry-capped at 16/32 waves (grid = batch = 256 = CU count,
// 1 block/CU).  Pipe work ~3.2K cyc/SIMD vs ~12.5K cyc critical path; the
// slack is dependency latency + barrier drain that no measured lever fills
// (R26 shfl-softmax regressed: bpermute = LDS pipe; R28 2-blocks/CU
// impossible; R25 stream cut -64KB -> -5us; R30 VALU cut -> 0).
// Session ladder: 669.8 -> 476 (wave-width split) -> 448 (T2-LDS slice) ->
// 392 (4-row) -> 374 (2-row) -> 372 (i8 K=64) -> 348.7 (T1 i4)  [floor].
// Config: 256 blocks x 1 row, 16 waves, i8-MFMA K=64, 3 barriers/eval,
// T1 i4 global (128 KB/eval, biased +8, softmax shift-invariant),
// T2 i8 signed: ct<36 LDS (147K) / ct>=36 global.  absmax 0.015625.

typedef __attribute__((ext_vector_type(4))) float f32x4;
typedef __attribute__((ext_vector_type(4))) int   i32x4;
typedef __attribute__((ext_vector_type(8))) short bf16x8;

struct TCons { float s[64]; float c[64]; };

__device__ __forceinline__ unsigned short f2bf(float f) {
  unsigned u = __builtin_bit_cast(unsigned, f);
  return (unsigned short)((u + 0x7FFFu + ((u >> 16) & 1u)) >> 16);
}
// pack 4 floats (|v|<=1) -> 4 i8 bytes scaled x127, LSB first
__device__ __forceinline__ int pk4i8(const float* v) {
  int a = __float2int_rn(v[0]*127.0f) & 255;
  int b = __float2int_rn(v[1]*127.0f) & 255;
  int c = __float2int_rn(v[2]*127.0f) & 255;
  int d = __float2int_rn(v[3]*127.0f);
  return a | (b << 8) | (c << 16) | (d << 24);
}

#define A1_OFF    0        // feats: GEMM1 i8 [cos 1024 | sin 1024]; epilogue bf16 [cos 2048 | sin 2048]
#define MBUF_OFF  4096     // m partials i32: 2 kh x 132 (kh stride 528) = 1056
#define W_OFF     5152     // w i8 (x127): 128 B (1 row)
#define ZP_OFF    5408     // 16 B zero page (bf16 epilogue pad cols)
#define XST_OFF   5424     // 104 chunks x 16 B bf16 (encoder prologue only)
#define T2L_OFF   7104     // T2 i8 ct 0..35: 72 frag-pairs x 2048 B = 147456
#define RED_OFF   7104     // epilogue overlay (T2L dead by then): 16 KiB
#define LDS_BYTES 154560   // ~151 KiB of 160 KiB

__global__
__attribute__((amdgpu_flat_work_group_size(1024, 1024), amdgpu_waves_per_eu(4, 4)))
void phasenn_kernel(
    const float* __restrict__ x, const float* __restrict__ W_enc,
    const float* __restrict__ b_enc, const float* __restrict__ xi,
    const float* __restrict__ W_out, const float* __restrict__ b_out,
    float* __restrict__ dout, char* __restrict__ wsb, TCons tc)
{
  __shared__ __align__(16) char smem[LDS_BYTES];

  const int tid  = threadIdx.x;
  const int bk   = blockIdx.x;        // batch row bk
  const int w    = tid >> 6;          // 16 waves
  const int lane = tid & 63;
  const int q    = lane >> 4;
  const int b16  = lane & 15;         // MFMA col slot (batch row duplicated x16)
  const int j4   = b16 >> 2;          // lane's n-subtile j / GEMM2 ct select
  const int r4   = b16 & 3;           // lane's r within the D reg quad
  const int nph  = (w*4 + j4)*16 + q*4 + r4;   // the ONE phase this lane owns

  char* T1g = wsb;                    // 128 KiB: (pt 8, F 16) i4 frags x 64 lanes x 16 B
  char* T2g = wsb + (256 << 10);      // ct>=36: (ct*2+P2) frag-pairs, 2 planes x 1024 (i8)

  // ---- LDS init: zero page only
  if (tid < 4) *(unsigned*)(smem + ZP_OFF + tid*4) = 0;

  // ---- xstage: x row bk -> bf16 B-frag chunks (linear), d>=784 zero (encoder)
  if (tid < 100) {
    const int dg = tid;
    bf16x8 fr = {0,0,0,0,0,0,0,0};
    if (dg < 98) {
      f32x4 v0 = *(const f32x4*)(x + (size_t)bk*784 + dg*8);
      f32x4 v1 = *(const f32x4*)(x + (size_t)bk*784 + dg*8 + 4);
      #pragma unroll
      for (int i = 0; i < 8; ++i) fr[i] = (short)f2bf(i < 4 ? v0[i] : v1[i-4]);
    }
    *(bf16x8*)(smem + XST_OFF + (dg << 4)) = fr;
  }

  // ---- table gen
  if (w < 8) {  // T1 i4: lane: p = w*16+b16, n = F*64 + q*16 + i; u = c*7+8
    const int p = w*16 + b16;
    for (int F = 0; F < 16; ++F) {
      const int n0 = F*64 + q*16;
      f32x4 v0 = *(const f32x4*)(xi + p*1024 + n0);
      f32x4 v1 = *(const f32x4*)(xi + p*1024 + n0 + 4);
      f32x4 v2 = *(const f32x4*)(xi + p*1024 + n0 + 8);
      f32x4 v3 = *(const f32x4*)(xi + p*1024 + n0 + 12);
      int cu[16], su[16];
      #pragma unroll
      for (int i = 0; i < 16; ++i) {
        float xv = (i < 4) ? v0[i] : (i < 8) ? v1[i-4] : (i < 12) ? v2[i-8] : v3[i-12];
        su[i] = __float2int_rn(__sinf(xv)*7.0f) + 8;   // 1..15
        cu[i] = __float2int_rn(__cosf(xv)*7.0f) + 8;
      }
      // pack: dword d covers k-group d*8; byte i = u[g+i] | u[g+i+4]<<4
      unsigned pc0=0, pc1=0, ps0=0, ps1=0;
      #pragma unroll
      for (int i = 0; i < 4; ++i) {
        pc0 |= (unsigned)(cu[i]     | (cu[i+4]  << 4)) << (8*i);
        pc1 |= (unsigned)(cu[8+i]   | (cu[12+i] << 4)) << (8*i);
        ps0 |= (unsigned)(su[i]     | (su[i+4]  << 4)) << (8*i);
        ps1 |= (unsigned)(su[8+i]   | (su[12+i] << 4)) << (8*i);
      }
      i32x4 P = {(int)pc0, (int)pc1, (int)ps0, (int)ps1};
      *(i32x4*)(T1g + (size_t)(w*16 + F)*1024 + lane*16) = P;
    }
  } else {      // T2 i8 (signed): lane: n = ct*16+b16, p = P2*64 + q*16 + i
    const int w2 = w - 8;
    for (int f = 0; f < 16; ++f) {
      const int ct = w2*8 + (f >> 1), P2 = f & 1;
      const int n = ct*16 + b16;
      float cv[16], sv[16];
      #pragma unroll
      for (int i = 0; i < 16; ++i) {
        float xv = xi[(P2*64 + q*16 + i)*1024 + n];
        sv[i] = __sinf(xv); cv[i] = __cosf(xv);
      }
      i32x4 C = { pk4i8(cv), pk4i8(cv+4), pk4i8(cv+8), pk4i8(cv+12) };
      i32x4 S = { pk4i8(sv), pk4i8(sv+4), pk4i8(sv+8), pk4i8(sv+12) };
      char* dst = (ct < 36)
          ? (smem + T2L_OFF + (size_t)(ct*2 + P2)*2048 + lane*16)
          : (T2g + (size_t)(ct*2 + P2)*2048 + lane*16);
      *(i32x4*)(dst) = C; *(i32x4*)(dst + 1024) = S;
    }
  }
  __syncthreads();

  // ---- encoder (bf16 MFMA): B cols all duplicate row bk; lane keeps 1 phase.
  float p0, ka, pwv;
  {
    f32x4 pac[4] = {{0,0,0,0},{0,0,0,0},{0,0,0,0},{0,0,0,0}};
    for (int kt = 0; kt < 25; ++kt) {
      bf16x8 bfr = *(const bf16x8*)(smem + XST_OFF + ((kt*4 + q) << 4));
      const int d = kt*32 + q*8;
      #pragma unroll
      for (int j = 0; j < 4; ++j) {
        bf16x8 afr = {0,0,0,0,0,0,0,0};
        if (d < 784) {
          const int n = (w*4 + j)*16 + b16;
          f32x4 v0 = *(const f32x4*)(W_enc + n*784 + d);
          f32x4 v1 = *(const f32x4*)(W_enc + n*784 + d + 4);
          #pragma unroll
          for (int i = 0; i < 8; ++i) afr[i] = (short)f2bf(i < 4 ? v0[i] : v1[i-4]);
        }
        pac[j] = __builtin_amdgcn_mfma_f32_16x16x32_bf16(afr, bfr, pac[j], 0, 0, 0);
      }
    }
    f32x4 pc = (j4==0) ? pac[0] : (j4==1) ? pac[1] : (j4==2) ? pac[2] : pac[3];
    float vA = (r4==0) ? pc[0] : (r4==1) ? pc[1] : (r4==2) ? pc[2] : pc[3];
    float ph = 6.283185307179586f / (1.0f + __expf(-(vA + b_enc[nph])));
    p0 = ph; pwv = ph; ka = 0.0f;
  }

  const float dtf = 0.03125f, half = 0.015625f;
  const float sixth = (float)(0.03125/6.0);
  const float mscale = (float)(2.0 / (1024.0 * 889.0));     // BETA/N / (7*127)
  const float kscale = (float)(1.0 / 16129.0);              // 1/127^2

  char* a1wr = smem + A1_OFF + nph;   // per-lane feat byte address (constant)

  for (int e = 0; e < 64; ++e) {
    float csv, snv;
    // ---- Phase A: all 64 lanes, 1 phase each; 1 cos + 1 sin byte store
    {
      snv = __sinf(pwv);
      csv = __cosf(pwv);
      *(char*)(a1wr)        = (char)(__float2int_rn(csv*127.0f));
      *(char*)(a1wr + 1024) = (char)(__float2int_rn(snv*127.0f));
    }
    __syncthreads();

    // ---- GEMM1 i8 K=64 with i4 T1 (unpack = AND/SHR, biased +8); 16 MFMA/wave
    {
      const int pt = w & 7, kh = w >> 3;
      i32x4 accC = {0,0,0,0}, accS = {0,0,0,0};
      const char* t1b = T1g + (size_t)(pt*16 + kh*8)*1024 + lane*16;
      const char* a1b = smem + A1_OFF + kh*512 + q*16;
      const unsigned M = 0x0F0F0F0Fu;
      #pragma unroll
      for (int i2 = 0; i2 < 8; ++i2) {
        i32x4 pk = *(const i32x4*)(t1b + (size_t)i2*1024);
        i32x4 ca = { (int)((unsigned)pk[0] & M), (int)(((unsigned)pk[0] >> 4) & M),
                     (int)((unsigned)pk[1] & M), (int)(((unsigned)pk[1] >> 4) & M) };
        i32x4 sa = { (int)((unsigned)pk[2] & M), (int)(((unsigned)pk[2] >> 4) & M),
                     (int)((unsigned)pk[3] & M), (int)(((unsigned)pk[3] >> 4) & M) };
        i32x4 bc = *(const i32x4*)(a1b + i2*64);
        i32x4 bs = *(const i32x4*)(a1b + i2*64 + 1024);
        accC = __builtin_amdgcn_mfma_i32_16x16x64_i8(ca, bc, accC, 0, 0, 0);
        accS = __builtin_amdgcn_mfma_i32_16x16x64_i8(sa, bs, accS, 0, 0, 0);
      }
      if (b16 == 0) {
        i32x4 acc = accC + accS;
        *(i32x4*)(smem + MBUF_OFF + kh*528 + ((pt*16 + q*4) << 2)) = acc;
      }
    }
    __syncthreads();

    // ---- softmax (wave 0): m' = m*889 + 8*Sum(f) (bias p-independent ->
    // softmax shift-invariant); w i8 (x127)
    if (w == 0) {
      const char* mb = smem + MBUF_OFF + lane*8;
      int a0 = *(const int*)(mb),       a1 = *(const int*)(mb + 4);
      int b0 = *(const int*)(mb + 528), b1 = *(const int*)(mb + 528 + 4);
      float e0 = __expf((float)(a0 + b0) * mscale);
      float e1 = __expf((float)(a1 + b1) * mscale);
      float s = e0 + e1;
      #pragma unroll
      for (int off = 1; off < 64; off <<= 1) s += __shfl_xor(s, off, 64);
      const float inv = 127.0f / s;
      int w0 = __float2int_rn(e0 * inv);
      int w1 = __float2int_rn(e1 * inv);
      *(unsigned short*)(smem + W_OFF + lane*2) =
          (unsigned short)((w0 & 255) | (w1 << 8));
    }
    __syncthreads();

    // ---- GEMM2 i8 K=64 + RK4: waves 0..8 LDS, 9..15 global; cached trig.
    {
      const float swt = tc.s[e], cwt = tc.c[e];
      const int st = e & 3;
      i32x4 wf0 = *(const i32x4*)(smem + W_OFF + q*16);
      i32x4 wf1 = *(const i32x4*)(smem + W_OFF + 64 + q*16);
      i32x4 aC[4] = {{0,0,0,0},{0,0,0,0},{0,0,0,0},{0,0,0,0}};
      i32x4 aS[4] = {{0,0,0,0},{0,0,0,0},{0,0,0,0},{0,0,0,0}};
      if (w < 9) {
        const char* t2b = smem + T2L_OFF + (size_t)(w*8)*2048 + lane*16;
        #pragma unroll
        for (int c = 0; c < 4; ++c)
          #pragma unroll
          for (int P2 = 0; P2 < 2; ++P2) {
            i32x4 ct_ = *(const i32x4*)(t2b + (size_t)(c*2 + P2)*2048);
            i32x4 st_ = *(const i32x4*)(t2b + (size_t)(c*2 + P2)*2048 + 1024);
            i32x4 wf = P2 ? wf1 : wf0;
            aC[c] = __builtin_amdgcn_mfma_i32_16x16x64_i8(ct_, wf, aC[c], 0, 0, 0);
            aS[c] = __builtin_amdgcn_mfma_i32_16x16x64_i8(st_, wf, aS[c], 0, 0, 0);
          }
      } else {
        const char* t2b = T2g + (size_t)(w*8)*2048 + lane*16;
        #pragma unroll
        for (int c = 0; c < 4; ++c)
          #pragma unroll
          for (int P2 = 0; P2 < 2; ++P2) {
            i32x4 ct_ = *(const i32x4*)(t2b + (size_t)(c*2 + P2)*2048);
            i32x4 st_ = *(const i32x4*)(t2b + (size_t)(c*2 + P2)*2048 + 1024);
            i32x4 wf = P2 ? wf1 : wf0;
            aC[c] = __builtin_amdgcn_mfma_i32_16x16x64_i8(ct_, wf, aC[c], 0, 0, 0);
            aS[c] = __builtin_amdgcn_mfma_i32_16x16x64_i8(st_, wf, aS[c], 0, 0, 0);
          }
      }
      i32x4 c4 = (j4==0) ? aC[0] : (j4==1) ? aC[1] : (j4==2) ? aC[2] : aC[3];
      i32x4 s4 = (j4==0) ? aS[0] : (j4==1) ? aS[1] : (j4==2) ? aS[2] : aS[3];
      float vC = (float)((r4==0) ? c4[0] : (r4==1) ? c4[1] : (r4==2) ? c4[2] : c4[3]);
      float vS = (float)((r4==0) ? s4[0] : (r4==1) ? s4[1] : (r4==2) ? s4[2] : s4[3]);
      float kv = (snv*vC - csv*vS) * kscale
               + 0.08f*(swt*csv - cwt*snv);           // A*sin(wt - phi)
      if (st == 0)      { ka  = kv;           pwv = p0 + kv*half; }
      else if (st == 1) { ka += 2.0f*kv;      pwv = p0 + kv*half; }
      else if (st == 2) { ka += 2.0f*kv;      pwv = p0 + kv*dtf;  }
      else { ka += kv; p0 += ka*sixth; pwv = p0; }
    }
  }

  // ---- epilogue (bf16 MFMA): out = [cos phiT, sin phiT] @ W_out^T + b_out
  __syncthreads();
  {
    *(unsigned short*)(smem + A1_OFF + nph*2)        = f2bf(__cosf(p0));
    *(unsigned short*)(smem + A1_OFF + 2048 + nph*2) = f2bf(__sinf(p0));
  }
  __syncthreads();
  {  // D[cl][col] partial over this wave's 4 ktiles; A = W_out rows (cl<10, pad 0)
    f32x4 acc = {0.f, 0.f, 0.f, 0.f};
    #pragma unroll
    for (int i2 = 0; i2 < 4; ++i2) {
      const int kt = w*4 + i2;
      const int k = kt*32 + q*8;
      bf16x8 afr = {0,0,0,0,0,0,0,0};
      if (b16 < 10) {
        f32x4 v0 = *(const f32x4*)(W_out + b16*2048 + k);
        f32x4 v1 = *(const f32x4*)(W_out + b16*2048 + k + 4);
        #pragma unroll
        for (int i = 0; i < 8; ++i) afr[i] = (short)f2bf(i < 4 ? v0[i] : v1[i-4]);
      }
      const char* baddr = (b16 == 0)
          ? (smem + A1_OFF + ((kt*4 + q) << 4))
          : (smem + ZP_OFF);
      bf16x8 bfr = *(const bf16x8*)baddr;
      acc = __builtin_amdgcn_mfma_f32_16x16x32_bf16(afr, bfr, acc, 0, 0, 0);
    }
    *(f32x4*)(smem + RED_OFF + ((w*64 + lane) << 4)) = acc;
  }
  __syncthreads();
  if (tid < 64) {   // reduce 16 wave-partials; lane: col = tid&15, cl = (tid>>4)*4+r
    f32x4 s = {0.f, 0.f, 0.f, 0.f};
    #pragma unroll
    for (int w2 = 0; w2 < 16; ++w2)
      s += *(const f32x4*)(smem + RED_OFF + ((w2*64 + tid) << 4));
    const int b = tid & 15, q2 = tid >> 4;
    if (b == 0) {
      #pragma unroll
      for (int r = 0; r < 4; ++r) {
        const int cl = q2*4 + r;
        if (cl < 10)
          dout[(size_t)bk*10 + cl] = s[r] + b_out[cl];
      }
    }
  }
}

extern "C" void kernel_launch(void* const* d_in, const int* in_sizes, int n_in,
                              void* d_out, int out_size, void* d_ws, size_t ws_size,
                              hipStream_t stream) {
  (void)in_sizes; (void)n_in; (void)ws_size; (void)out_size;
  const float* x     = (const float*)d_in[0];
  const float* W_enc = (const float*)d_in[1];
  const float* b_enc = (const float*)d_in[2];
  const float* xi    = (const float*)d_in[3];
  const float* W_out = (const float*)d_in[4];
  const float* b_out = (const float*)d_in[5];
  float* out = (float*)d_out;
  char* wsb = (char*)d_ws;   // T1 i4 128K @0 | T2 i8 (ct>=36) @256K; rewritten per launch

  TCons tc;
  const double OME = 2.0 * 3.14159265358979323846 * 200.0;
  const double dtd = 0.03125;
  const double co[4] = {0.0, 0.5, 0.5, 1.0};
  for (int e = 0; e < 64; ++e) {
    double t = ((double)(e >> 2) + co[e & 3]) * dtd;
    tc.s[e] = (float)sin(OME * t);
    tc.c[e] = (float)cos(OME * t);
  }

  phasenn_kernel<<<dim3(256), dim3(1024), 0, stream>>>(
      x, W_enc, b_enc, xi, W_out, b_out, out, wsb, tc);
}